// Round 2
// 450.687 us; speedup vs baseline: 1.0265x; 1.0265x over previous
//
#include <hip/hip_runtime.h>

#define TT  2048
#define H   10
#define WU  128     // warmup steps for chunks k>0
#define NCH 3       // time-chunks per sequence
#define DT  640     // chunk start stride: t0 = DT*k
#define NS  768     // simulated steps per chunk (= DT + WU)
#define NC  48      // 16-step sub-chunks (NS/16)

typedef float f2 __attribute__((ext_vector_type(2)));
typedef float f4 __attribute__((ext_vector_type(4)));

__device__ __forceinline__ float ex2(float a)  { return __builtin_amdgcn_exp2f(a); }
__device__ __forceinline__ float rcpf(float a) { return __builtin_amdgcn_rcpf(a); }
__device__ __forceinline__ f2 fma2(f2 a, f2 b, f2 c) { return __builtin_elementwise_fma(a, b, c); }

// quad broadcast via DPP
template <int CTRL>
__device__ __forceinline__ float qb(float v) {
    int i = __float_as_int(v);
    return __int_as_float(__builtin_amdgcn_update_dpp(i, i, CTRL, 0xF, 0xF, true));
}

// R12: R11's 3-balanced-chunk geometry (serial depth 1152 -> 768, all blocks
// equal length) with the publish REVERTED to the R10-proven readlane path.
// R11's LDS-bounce publish produced absmax 0.21 (the chunk geometry was
// exhaustively re-audited and is sound; R10 proved WU=128 seam decay <= 5e-4,
// and seam statistics are position-independent) -- so the bounce is the
// suspect and is withdrawn pending an isolated retry.
// Chunk k simulates t in [640k, 640k+768); k=0 writes [0,768), k=1 writes
// [768,1408), k=2 writes [1408,2048) (first WU=128 steps of k>0 are warmup,
// discarded; GRU contraction decays the h=0 init error below ~5e-4 by then).
// Grid 3072 x 128: 12 blocks/CU -> 6 waves/SIMD (1536 thr/CU, SGPR 12x2x112
// within pool, LDS 3 KiB/block). At 6 waves/SIMD the SIMD issue pipe is the
// shared resource; per-step period grows ~515 -> ~600 cyc but depth falls 33%.
__global__ __launch_bounds__(128)
__attribute__((amdgpu_waves_per_eu(1, 6)))
void gru_pipe_kernel(
    const float* __restrict__ X,
    const float* __restrict__ Wih0, const float* __restrict__ Whh0,
    const float* __restrict__ bih0, const float* __restrict__ bhh0,
    const float* __restrict__ Wih1, const float* __restrict__ Whh1,
    const float* __restrict__ bih1, const float* __restrict__ bhh1,
    const float* __restrict__ Wlin, const float* __restrict__ blin,
    float* __restrict__ OUT)
{
    const int seq = blockIdx.x / NCH;
    const int k   = blockIdx.x % NCH;
    const int t0  = DT * k;                 // first simulated timestep
    const int lo  = k ? (t0 + WU) : 0;      // first timestep we may write

    const int wv   = threadIdx.x >> 6;   // 0 = A (layer0), 1 = B (layer1+head)
    const int l    = threadIdx.x & 63;
    const int u    = l >> 2, role = l & 3;
    const float L2E = 1.44269504088896340736f;

    __shared__ __align__(16) float ring[768];   // 3 banks x 16 steps x 16 floats

    if (wv == 0) {
        // ---------------- wave A: layer 0 ----------------
        f2 wA[5];
        float bias = 0.f, wx = 0.f, wxn = 0.f, bxn = 0.f;
        #pragma unroll
        for (int j = 0; j < 5; ++j) wA[j] = (f2)(0.f);
        if (l < 40) {
            if (role == 0) {
                #pragma unroll
                for (int kk = 0; kk < H; ++kk) wA[kk >> 1][kk & 1] = -L2E * Whh0[u * H + kk];
                wx = -L2E * Wih0[u];  bias = -L2E * (bih0[u] + bhh0[u]);
            } else if (role == 1) {
                #pragma unroll
                for (int kk = 0; kk < H; ++kk) wA[kk >> 1][kk & 1] = -L2E * Whh0[(10 + u) * H + kk];
                wx = -L2E * Wih0[10 + u];  bias = -L2E * (bih0[10 + u] + bhh0[10 + u]);
            } else if (role == 2) {
                #pragma unroll
                for (int kk = 0; kk < H; ++kk) wA[kk >> 1][kk & 1] = 2.f * L2E * Whh0[(20 + u) * H + kk];
                bias = 2.f * L2E * bhh0[20 + u];
            }
            wxn = 2.f * L2E * Wih0[20 + u];  bxn = 2.f * L2E * bih0[20 + u];
        }
        const bool wrt = (l < 40) && (role == 0);

        f2 S1[5];
        #pragma unroll
        for (int j = 0; j < 5; ++j) S1[j] = (f2)(0.f);
        float hprev = 0.f;

        const float* Xp = X + seq * TT + t0;
        f4 xq0 = *(const f4*)(Xp);
        f4 xq1 = *(const f4*)(Xp + 4);

        for (int c = 0; c < NC + 2; ++c) {
            __syncthreads();
            if (c < NC) {
                float* rbase = &ring[(c % 3) * 256 + u];
                #pragma unroll
                for (int hf = 0; hf < 2; ++hf) {
                    int nxt = c * 16 + hf * 8 + 8;
                    if (nxt > NS - 8) nxt = NS - 8;
                    f4 xn0 = *(const f4*)(Xp + nxt);
                    f4 xn1 = *(const f4*)(Xp + nxt + 4);
                    #pragma unroll
                    for (int j = 0; j < 8; ++j) {
                        const float x = (j < 4) ? xq0[j] : xq1[j - 4];
                        f2 a = wA[0] * S1[0];
                        f2 b = wA[1] * S1[1];
                        a = fma2(wA[2], S1[2], a); b = fma2(wA[3], S1[3], b);
                        a = fma2(wA[4], S1[4], a);
                        f2 t = a + b;
                        float d = (t.x + t.y) + fmaf(wx, x, bias);
                        float dR  = qb<0x00>(d);
                        float dZ  = qb<0x55>(d);
                        float dNh = qb<0xAA>(d);
                        float dNx = fmaf(wxn, x, bxn);
                        float r = rcpf(1.f + ex2(dR));
                        float q = fmaf(r, dNh, dNx);
                        float n = fmaf(-2.f, rcpf(1.f + ex2(q)), 1.f);
                        float F = ex2(dZ);
                        float hnew = fmaf(F, n, hprev) * rcpf(1.f + F);
                        hprev = hnew;
                        const int hb = __float_as_int(hnew);
                        #pragma unroll
                        for (int jj = 0; jj < 5; ++jj) {
                            S1[jj] = f2{ __int_as_float(__builtin_amdgcn_readlane(hb, 8 * jj)),
                                         __int_as_float(__builtin_amdgcn_readlane(hb, 8 * jj + 4)) };
                        }
                        if (wrt) rbase[(hf * 8 + j) * 16] = hnew;
                    }
                    xq0 = xn0; xq1 = xn1;
                }
            }
        }
    } else {
        // ---------------- wave B: layer 1 + head ----------------
        f2 wA[5], wB[5];   // wA over h1 (LDS input), wB over h2 (SGPR state)
        float bias = 0.f;
        #pragma unroll
        for (int j = 0; j < 5; ++j) { wA[j] = (f2)(0.f); wB[j] = (f2)(0.f); }
        if (l < 40) {
            if (role == 0) {
                #pragma unroll
                for (int kk = 0; kk < H; ++kk) {
                    wA[kk >> 1][kk & 1] = -L2E * Wih1[u * H + kk];
                    wB[kk >> 1][kk & 1] = -L2E * Whh1[u * H + kk];
                }
                bias = -L2E * (bih1[u] + bhh1[u]);
            } else if (role == 1) {
                #pragma unroll
                for (int kk = 0; kk < H; ++kk) {
                    wA[kk >> 1][kk & 1] = -L2E * Wih1[(10 + u) * H + kk];
                    wB[kk >> 1][kk & 1] = -L2E * Whh1[(10 + u) * H + kk];
                }
                bias = -L2E * (bih1[10 + u] + bhh1[10 + u]);
            } else if (role == 2) {
                #pragma unroll
                for (int kk = 0; kk < H; ++kk) wB[kk >> 1][kk & 1] = 2.f * L2E * Whh1[(20 + u) * H + kk];
                bias = 2.f * L2E * bhh1[20 + u];
            } else {
                #pragma unroll
                for (int kk = 0; kk < H; ++kk) wA[kk >> 1][kk & 1] = 2.f * L2E * Wih1[(20 + u) * H + kk];
                bias = 2.f * L2E * bih1[20 + u];
            }
        } else if (l == 44) {      // output head (raw scale), dot over h2 only
            #pragma unroll
            for (int kk = 0; kk < H; ++kk) wB[kk >> 1][kk & 1] = Wlin[kk];
            bias = blin[0];
        }
        const bool hd = (l == 44);

        f2 S2[5];
        #pragma unroll
        for (int j = 0; j < 5; ++j) S2[j] = (f2)(0.f);
        float hprev = 0.f;
        f2 hc0, hc1, hc2, hc3, hc4;   // current h1[s]
        float om1 = 0.f;              // carry: previous head output
        float* Op = OUT + seq * TT;

        for (int c = 0; c < NC + 2; ++c) {
            __syncthreads();
            if (c >= 2) {
                const int c2 = c - 2;
                const float* rb  = &ring[(c2 % 3) * 256];
                const float* rbN = &ring[((c2 + 1) % 3) * 256];
                if (c2 == 0) {
                    const f4 a0 = *(const f4*)&rb[0];
                    const f4 a1 = *(const f4*)&rb[4];
                    const f2 a2 = *(const f2*)&rb[8];
                    hc0 = __builtin_shufflevector(a0, a0, 0, 1);
                    hc1 = __builtin_shufflevector(a0, a0, 2, 3);
                    hc2 = __builtin_shufflevector(a1, a1, 0, 1);
                    hc3 = __builtin_shufflevector(a1, a1, 2, 3);
                    hc4 = a2;
                }
                #pragma unroll
                for (int j = 0; j < 16; ++j) {
                    const int s = c2 * 16 + j;
                    const float* np = (j < 15) ? (rb + (j + 1) * 16) : rbN;
                    const f4 p0 = *(const f4*)&np[0];
                    const f4 p1 = *(const f4*)&np[4];
                    const f2 p2 = *(const f2*)&np[8];
                    // dual dot: chain a over h1 (ring regs), chain b over h2
                    f2 a = wA[0] * hc0;
                    f2 b = wB[0] * S2[0];
                    a = fma2(wA[1], hc1, a); b = fma2(wB[1], S2[1], b);
                    a = fma2(wA[2], hc2, a); b = fma2(wB[2], S2[2], b);
                    a = fma2(wA[3], hc3, a); b = fma2(wB[3], S2[3], b);
                    a = fma2(wA[4], hc4, a); b = fma2(wB[4], S2[4], b);
                    f2 t = a + b;
                    float d = (t.x + t.y) + bias;
                    float dR  = qb<0x00>(d);
                    float dZ  = qb<0x55>(d);
                    float dNh = qb<0xAA>(d);
                    float dNx = qb<0xFF>(d);
                    float r = rcpf(1.f + ex2(dR));
                    float q = fmaf(r, dNh, dNx);
                    float n = fmaf(-2.f, rcpf(1.f + ex2(q)), 1.f);
                    float F = ex2(dZ);
                    float hnew = fmaf(F, n, hprev) * rcpf(1.f + F);
                    hprev = hnew;
                    const int hb = __float_as_int(hnew);
                    #pragma unroll
                    for (int jj = 0; jj < 5; ++jj) {
                        S2[jj] = f2{ __int_as_float(__builtin_amdgcn_readlane(hb, 8 * jj)),
                                     __int_as_float(__builtin_amdgcn_readlane(hb, 8 * jj + 4)) };
                    }
                    // head: d = out[t0+s-1]; paired store at even s covers
                    // {out[t0+s-2], out[t0+s-1]}, gated to t >= lo (warmup
                    // outputs of chunks k>0 are discarded, not written).
                    if ((j & 1) == 0) {
                        const int ot = t0 + s - 2;
                        if (hd && ot >= lo) *(f2*)(Op + ot) = f2{om1, d};
                    }
                    om1 = d;
                    hc0 = __builtin_shufflevector(p0, p0, 0, 1);
                    hc1 = __builtin_shufflevector(p0, p0, 2, 3);
                    hc2 = __builtin_shufflevector(p1, p1, 0, 1);
                    hc3 = __builtin_shufflevector(p1, p1, 2, 3);
                    hc4 = p2;
                }
            }
        }
        // tail: out[t0+NS-1] from final h2; om1 = out[t0+NS-2]
        {
            f2 b = wB[0] * S2[0];
            b = fma2(wB[1], S2[1], b);
            b = fma2(wB[2], S2[2], b);
            b = fma2(wB[3], S2[3], b);
            b = fma2(wB[4], S2[4], b);
            float d = (b.x + b.y) + bias;
            if (hd) *(f2*)(Op + t0 + NS - 2) = f2{om1, d};
        }
    }
}

extern "C" void kernel_launch(void* const* d_in, const int* in_sizes, int n_in,
                              void* d_out, int out_size, void* d_ws, size_t ws_size,
                              hipStream_t stream) {
    const float* X    = (const float*)d_in[0];
    const float* Wih0 = (const float*)d_in[1];
    const float* Whh0 = (const float*)d_in[2];
    const float* bih0 = (const float*)d_in[3];
    const float* bhh0 = (const float*)d_in[4];
    const float* Wih1 = (const float*)d_in[5];
    const float* Whh1 = (const float*)d_in[6];
    const float* bih1 = (const float*)d_in[7];
    const float* bhh1 = (const float*)d_in[8];
    const float* Wlin = (const float*)d_in[9];
    const float* blin = (const float*)d_in[10];

    gru_pipe_kernel<<<NCH * 1024, 128, 0, stream>>>(X, Wih0, Whh0, bih0, bhh0,
                                                    Wih1, Whh1, bih1, bhh1, Wlin, blin,
                                                    (float*)d_out);
}

// Round 3
// 376.218 us; speedup vs baseline: 1.2297x; 1.1979x over previous
//
#include <hip/hip_runtime.h>

#define TT  2048
#define H   10
#define WU  128     // warmup steps for chunks k>0
#define NCH 3       // time-chunks per sequence
#define DT  640     // chunk start stride: t0 = DT*k
#define NS  768     // simulated steps per chunk (= DT + WU)
#define NC  48      // 16-step sub-chunks (NS/16)

typedef float f2 __attribute__((ext_vector_type(2)));
typedef float f4 __attribute__((ext_vector_type(4)));

__device__ __forceinline__ float ex2(float a)  { return __builtin_amdgcn_exp2f(a); }
__device__ __forceinline__ float rcpf(float a) { return __builtin_amdgcn_rcpf(a); }
__device__ __forceinline__ f2 fma2(f2 a, f2 b, f2 c) { return __builtin_elementwise_fma(a, b, c); }

// quad broadcast via DPP
template <int CTRL>
__device__ __forceinline__ float qb(float v) {
    int i = __float_as_int(v);
    return __int_as_float(__builtin_amdgcn_update_dpp(i, i, CTRL, 0xF, 0xF, true));
}

// R13: R12 geometry (3 balanced chunks, depth 768) + LDS-bounce publish,
// retried as an ISOLATED change with the R11 root cause fixed. R11's failure
// mechanism: the bounce wrote h via float* and read back via f4*/f2*; TBAA
// treats these as non-aliasing, so clang could sink the ds_write past the
// ds_read (or hoist the read) -- stale-state broadcast, absmax 0.21. Fix:
// asm volatile("" ::: "memory") between write and readback pins program
// order; the LDS pipe then guarantees same-wave write->read ordering in HW.
// Why bounce at all: R12 counters show the system is VALU-issue-bound
// (VALUBusy 85.5%, per-wave-step issue ~184 cyc invariant across R10/R12).
// The readlane publish is 10 v_readlane + ~10 v_mov = ~20 VALU slots/step.
// Bounce replaces it with 3-4 DS ops (separate pipe): wave A re-reads its own
// ring write (+3 ds_read, write already exists), wave B bounces h2 through a
// 16-float buffer (+1 ds_write, +3 ds_read). Broadcast reads = conflict-free.
__global__ __launch_bounds__(128)
__attribute__((amdgpu_waves_per_eu(1, 6)))
void gru_pipe_kernel(
    const float* __restrict__ X,
    const float* __restrict__ Wih0, const float* __restrict__ Whh0,
    const float* __restrict__ bih0, const float* __restrict__ bhh0,
    const float* __restrict__ Wih1, const float* __restrict__ Whh1,
    const float* __restrict__ bih1, const float* __restrict__ bhh1,
    const float* __restrict__ Wlin, const float* __restrict__ blin,
    float* __restrict__ OUT)
{
    const int seq = blockIdx.x / NCH;
    const int k   = blockIdx.x % NCH;
    const int t0  = DT * k;                 // first simulated timestep
    const int lo  = k ? (t0 + WU) : 0;      // first timestep we may write

    const int wv   = threadIdx.x >> 6;   // 0 = A (layer0), 1 = B (layer1+head)
    const int l    = threadIdx.x & 63;
    const int u    = l >> 2, role = l & 3;
    const float L2E = 1.44269504088896340736f;

    __shared__ __align__(16) float ring[768];   // 3 banks x 16 steps x 16 floats
    __shared__ __align__(16) float h2b[16];     // wave-B h2 bounce buffer

    if (wv == 0) {
        // ---------------- wave A: layer 0 ----------------
        f2 wA[5];
        float bias = 0.f, wx = 0.f, wxn = 0.f, bxn = 0.f;
        #pragma unroll
        for (int j = 0; j < 5; ++j) wA[j] = (f2)(0.f);
        if (l < 40) {
            if (role == 0) {
                #pragma unroll
                for (int kk = 0; kk < H; ++kk) wA[kk >> 1][kk & 1] = -L2E * Whh0[u * H + kk];
                wx = -L2E * Wih0[u];  bias = -L2E * (bih0[u] + bhh0[u]);
            } else if (role == 1) {
                #pragma unroll
                for (int kk = 0; kk < H; ++kk) wA[kk >> 1][kk & 1] = -L2E * Whh0[(10 + u) * H + kk];
                wx = -L2E * Wih0[10 + u];  bias = -L2E * (bih0[10 + u] + bhh0[10 + u]);
            } else if (role == 2) {
                #pragma unroll
                for (int kk = 0; kk < H; ++kk) wA[kk >> 1][kk & 1] = 2.f * L2E * Whh0[(20 + u) * H + kk];
                bias = 2.f * L2E * bhh0[20 + u];
            }
            wxn = 2.f * L2E * Wih0[20 + u];  bxn = 2.f * L2E * bih0[20 + u];
        }
        const bool wrt = (l < 40) && (role == 0);

        f2 S1[5];
        #pragma unroll
        for (int j = 0; j < 5; ++j) S1[j] = (f2)(0.f);
        float hprev = 0.f;

        const float* Xp = X + seq * TT + t0;
        f4 xq0 = *(const f4*)(Xp);
        f4 xq1 = *(const f4*)(Xp + 4);

        for (int c = 0; c < NC + 2; ++c) {
            __syncthreads();
            if (c < NC) {
                float* rw = &ring[(c % 3) * 256];   // this chunk's ring bank
                #pragma unroll
                for (int hf = 0; hf < 2; ++hf) {
                    int nxt = c * 16 + hf * 8 + 8;
                    if (nxt > NS - 8) nxt = NS - 8;
                    f4 xn0 = *(const f4*)(Xp + nxt);
                    f4 xn1 = *(const f4*)(Xp + nxt + 4);
                    #pragma unroll
                    for (int j = 0; j < 8; ++j) {
                        const float x = (j < 4) ? xq0[j] : xq1[j - 4];
                        f2 a = wA[0] * S1[0];
                        f2 b = wA[1] * S1[1];
                        a = fma2(wA[2], S1[2], a); b = fma2(wA[3], S1[3], b);
                        a = fma2(wA[4], S1[4], a);
                        f2 t = a + b;
                        float d = (t.x + t.y) + fmaf(wx, x, bias);
                        float dR  = qb<0x00>(d);
                        float dZ  = qb<0x55>(d);
                        float dNh = qb<0xAA>(d);
                        float dNx = fmaf(wxn, x, bxn);
                        float r = rcpf(1.f + ex2(dR));
                        float q = fmaf(r, dNh, dNx);
                        float n = fmaf(-2.f, rcpf(1.f + ex2(q)), 1.f);
                        float F = ex2(dZ);
                        float hnew = fmaf(F, n, hprev) * rcpf(1.f + F);
                        hprev = hnew;
                        const int st = hf * 8 + j;
                        // publish: role-0 lanes write own h element to ring
                        // (doubles as the layer-1 handoff), then ALL lanes
                        // read the vector back. Fence pins ds_write before
                        // ds_read (TBAA would otherwise allow reordering);
                        // LDS pipe is in-order within a wave.
                        if (wrt) rw[st * 16 + u] = hnew;
                        asm volatile("" ::: "memory");
                        const float* sp = rw + st * 16;
                        const f4 s0 = *(const f4*)sp;
                        const f4 s1 = *(const f4*)(sp + 4);
                        const f2 s2 = *(const f2*)(sp + 8);
                        S1[0] = __builtin_shufflevector(s0, s0, 0, 1);
                        S1[1] = __builtin_shufflevector(s0, s0, 2, 3);
                        S1[2] = __builtin_shufflevector(s1, s1, 0, 1);
                        S1[3] = __builtin_shufflevector(s1, s1, 2, 3);
                        S1[4] = s2;
                    }
                    xq0 = xn0; xq1 = xn1;
                }
            }
        }
    } else {
        // ---------------- wave B: layer 1 + head ----------------
        f2 wA[5], wB[5];   // wA over h1 (LDS input), wB over h2 (bounced state)
        float bias = 0.f;
        #pragma unroll
        for (int j = 0; j < 5; ++j) { wA[j] = (f2)(0.f); wB[j] = (f2)(0.f); }
        if (l < 40) {
            if (role == 0) {
                #pragma unroll
                for (int kk = 0; kk < H; ++kk) {
                    wA[kk >> 1][kk & 1] = -L2E * Wih1[u * H + kk];
                    wB[kk >> 1][kk & 1] = -L2E * Whh1[u * H + kk];
                }
                bias = -L2E * (bih1[u] + bhh1[u]);
            } else if (role == 1) {
                #pragma unroll
                for (int kk = 0; kk < H; ++kk) {
                    wA[kk >> 1][kk & 1] = -L2E * Wih1[(10 + u) * H + kk];
                    wB[kk >> 1][kk & 1] = -L2E * Whh1[(10 + u) * H + kk];
                }
                bias = -L2E * (bih1[10 + u] + bhh1[10 + u]);
            } else if (role == 2) {
                #pragma unroll
                for (int kk = 0; kk < H; ++kk) wB[kk >> 1][kk & 1] = 2.f * L2E * Whh1[(20 + u) * H + kk];
                bias = 2.f * L2E * bhh1[20 + u];
            } else {
                #pragma unroll
                for (int kk = 0; kk < H; ++kk) wA[kk >> 1][kk & 1] = 2.f * L2E * Wih1[(20 + u) * H + kk];
                bias = 2.f * L2E * bih1[20 + u];
            }
        } else if (l == 44) {      // output head (raw scale), dot over h2 only
            #pragma unroll
            for (int kk = 0; kk < H; ++kk) wB[kk >> 1][kk & 1] = Wlin[kk];
            bias = blin[0];
        }
        const bool hd = (l == 44);
        const bool w2 = (l < 40) && (role == 0);

        f2 S2[5];
        #pragma unroll
        for (int j = 0; j < 5; ++j) S2[j] = (f2)(0.f);
        float hprev = 0.f;
        f2 hc0, hc1, hc2, hc3, hc4;   // current h1[s]
        float om1 = 0.f;              // carry: previous head output
        float* Op = OUT + seq * TT;

        for (int c = 0; c < NC + 2; ++c) {
            __syncthreads();
            if (c >= 2) {
                const int c2 = c - 2;
                const float* rb  = &ring[(c2 % 3) * 256];
                const float* rbN = &ring[((c2 + 1) % 3) * 256];
                if (c2 == 0) {
                    const f4 a0 = *(const f4*)&rb[0];
                    const f4 a1 = *(const f4*)&rb[4];
                    const f2 a2 = *(const f2*)&rb[8];
                    hc0 = __builtin_shufflevector(a0, a0, 0, 1);
                    hc1 = __builtin_shufflevector(a0, a0, 2, 3);
                    hc2 = __builtin_shufflevector(a1, a1, 0, 1);
                    hc3 = __builtin_shufflevector(a1, a1, 2, 3);
                    hc4 = a2;
                }
                #pragma unroll
                for (int j = 0; j < 16; ++j) {
                    const int s = c2 * 16 + j;
                    const float* np = (j < 15) ? (rb + (j + 1) * 16) : rbN;
                    const f4 p0 = *(const f4*)&np[0];
                    const f4 p1 = *(const f4*)&np[4];
                    const f2 p2 = *(const f2*)&np[8];
                    // dual dot: chain a over h1 (ring regs), chain b over h2
                    f2 a = wA[0] * hc0;
                    f2 b = wB[0] * S2[0];
                    a = fma2(wA[1], hc1, a); b = fma2(wB[1], S2[1], b);
                    a = fma2(wA[2], hc2, a); b = fma2(wB[2], S2[2], b);
                    a = fma2(wA[3], hc3, a); b = fma2(wB[3], S2[3], b);
                    a = fma2(wA[4], hc4, a); b = fma2(wB[4], S2[4], b);
                    f2 t = a + b;
                    float d = (t.x + t.y) + bias;
                    float dR  = qb<0x00>(d);
                    float dZ  = qb<0x55>(d);
                    float dNh = qb<0xAA>(d);
                    float dNx = qb<0xFF>(d);
                    float r = rcpf(1.f + ex2(dR));
                    float q = fmaf(r, dNh, dNx);
                    float n = fmaf(-2.f, rcpf(1.f + ex2(q)), 1.f);
                    float F = ex2(dZ);
                    float hnew = fmaf(F, n, hprev) * rcpf(1.f + F);
                    hprev = hnew;
                    // publish h2 via LDS bounce (replaces 10x readlane).
                    // Fence pins ds_write before ds_read; same-wave LDS ops
                    // are in-order in HW.
                    if (w2) h2b[u] = hnew;
                    asm volatile("" ::: "memory");
                    const f4 t0v = *(const f4*)&h2b[0];
                    const f4 t1v = *(const f4*)&h2b[4];
                    const f2 t2v = *(const f2*)&h2b[8];
                    S2[0] = __builtin_shufflevector(t0v, t0v, 0, 1);
                    S2[1] = __builtin_shufflevector(t0v, t0v, 2, 3);
                    S2[2] = __builtin_shufflevector(t1v, t1v, 0, 1);
                    S2[3] = __builtin_shufflevector(t1v, t1v, 2, 3);
                    S2[4] = t2v;
                    // head: d = out[t0+s-1]; paired store at even s covers
                    // {out[t0+s-2], out[t0+s-1]}, gated to t >= lo (warmup
                    // outputs of chunks k>0 are discarded, not written).
                    if ((j & 1) == 0) {
                        const int ot = t0 + s - 2;
                        if (hd && ot >= lo) *(f2*)(Op + ot) = f2{om1, d};
                    }
                    om1 = d;
                    hc0 = __builtin_shufflevector(p0, p0, 0, 1);
                    hc1 = __builtin_shufflevector(p0, p0, 2, 3);
                    hc2 = __builtin_shufflevector(p1, p1, 0, 1);
                    hc3 = __builtin_shufflevector(p1, p1, 2, 3);
                    hc4 = p2;
                }
            }
        }
        // tail: out[t0+NS-1] from final h2; om1 = out[t0+NS-2]
        {
            f2 b = wB[0] * S2[0];
            b = fma2(wB[1], S2[1], b);
            b = fma2(wB[2], S2[2], b);
            b = fma2(wB[3], S2[3], b);
            b = fma2(wB[4], S2[4], b);
            float d = (b.x + b.y) + bias;
            if (hd) *(f2*)(Op + t0 + NS - 2) = f2{om1, d};
        }
    }
}

extern "C" void kernel_launch(void* const* d_in, const int* in_sizes, int n_in,
                              void* d_out, int out_size, void* d_ws, size_t ws_size,
                              hipStream_t stream) {
    const float* X    = (const float*)d_in[0];
    const float* Wih0 = (const float*)d_in[1];
    const float* Whh0 = (const float*)d_in[2];
    const float* bih0 = (const float*)d_in[3];
    const float* bhh0 = (const float*)d_in[4];
    const float* Wih1 = (const float*)d_in[5];
    const float* Whh1 = (const float*)d_in[6];
    const float* bih1 = (const float*)d_in[7];
    const float* bhh1 = (const float*)d_in[8];
    const float* Wlin = (const float*)d_in[9];
    const float* blin = (const float*)d_in[10];

    gru_pipe_kernel<<<NCH * 1024, 128, 0, stream>>>(X, Wih0, Whh0, bih0, bhh0,
                                                    Wih1, Whh1, bih1, bhh1, Wlin, blin,
                                                    (float*)d_out);
}